// Round 7
// baseline (891.859 us; speedup 1.0000x reference)
//
#include <hip/hip_runtime.h>
#include <hip/hip_fp16.h>

#define G_ 512
#define B_ 64
#define I_ 32
#define H_ 64
#define NGATE 256  // 4*H

typedef _Float16 half8 __attribute__((ext_vector_type(8)));
typedef _Float16 h4 __attribute__((ext_vector_type(4)));
typedef _Float16 h2 __attribute__((ext_vector_type(2)));
typedef float f32x4 __attribute__((ext_vector_type(4)));

#if __has_builtin(__builtin_amdgcn_fdot2)
#define FDOT2(a, b, c) __builtin_amdgcn_fdot2((a), (b), (c), false)
#else
#define FDOT2(a, b, c) ((c) + (float)(a)[0] * (float)(b)[0] + (float)(a)[1] * (float)(b)[1])
#endif

__device__ __forceinline__ float sigf(float x) {
  return 1.0f / (1.0f + __expf(-x));
}
__device__ __forceinline__ float tanh_fast(float x) {
  x = fminf(fmaxf(x, -15.0f), 15.0f);
  float e = __expf(2.0f * x);
  return (e - 1.0f) / (e + 1.0f);
}

// ---------------- K1: xproj[b][g][col*4+q]  (coalesced 8B-per-lane scan reads)
__global__ __launch_bounds__(256) void k_xproj(
    const float* __restrict__ input, const float* __restrict__ W_ih,
    const float* __restrict__ b_ih, const float* __restrict__ b_hh,
    _Float16* __restrict__ xproj) {
  const int g = blockIdx.x;
  const int t = threadIdx.x;
  const int col = t >> 2;
  const int q = t & 3;
  const int row = q * H_ + col;  // gate-row in torch i,f,g,o order
  __shared__ alignas(16) float inp[B_ * I_];
  const float* ing = input + (size_t)g * (B_ * I_);
#pragma unroll
  for (int u = 0; u < (B_ * I_) / 256; ++u) inp[u * 256 + t] = ing[u * 256 + t];
  float w[I_];
#pragma unroll
  for (int k = 0; k < I_; k += 4) {
    f32x4 v = *(const f32x4*)(W_ih + (size_t)row * I_ + k);
    w[k] = v[0]; w[k + 1] = v[1]; w[k + 2] = v[2]; w[k + 3] = v[3];
  }
  const float bias = b_ih[row] + b_hh[row];
  __syncthreads();
  for (int b = 0; b < B_; ++b) {
    float a0 = bias, a1 = 0.f, a2 = 0.f, a3 = 0.f;
#pragma unroll
    for (int k = 0; k < I_; k += 4) {
      f32x4 iv = *(const f32x4*)&inp[b * I_ + k];
      a0 += iv[0] * w[k]; a1 += iv[1] * w[k + 1];
      a2 += iv[2] * w[k + 2]; a3 += iv[3] * w[k + 3];
    }
    xproj[((size_t)b * G_ + g) * NGATE + t] = (_Float16)((a0 + a1) + (a2 + a3));
  }
}

// ---------------- K2: LSTM scan, TWO batch rows per wave (ILP dual pipeline).
// The two rows' dot/activation chains are independent; interleaving them hides
// the LDS round-trip + transcendental latency that dominates (1186 cyc/step
// measured vs ~300 issue floor). W_hh registers are shared between the rows.
__global__ __launch_bounds__(64) void k_scan(
    const _Float16* __restrict__ xproj, const float* __restrict__ h0,
    const float* __restrict__ c0, const float* __restrict__ W_hh,
    _Float16* __restrict__ hs) {
  const int b0 = blockIdx.x * 2;  // rows b0, b0+1
  const int j = threadIdx.x;      // 0..63
  __shared__ alignas(16) _Float16 hsh[2][H_];

  h2 w[4][32];
#pragma unroll
  for (int q = 0; q < 4; ++q) {
    const f32x4* wr = (const f32x4*)(W_hh + (size_t)(q * H_ + j) * H_);
#pragma unroll
    for (int kk = 0; kk < 16; ++kk) {
      f32x4 v = wr[kk];
      h2 t0, t1;
      t0[0] = (_Float16)v[0]; t0[1] = (_Float16)v[1];
      t1[0] = (_Float16)v[2]; t1[1] = (_Float16)v[3];
      w[q][2 * kk] = t0;
      w[q][2 * kk + 1] = t1;
    }
  }
  float cA = c0[b0 * H_ + j];
  float cB = c0[(b0 + 1) * H_ + j];
  hsh[0][j] = (_Float16)h0[b0 * H_ + j];
  hsh[1][j] = (_Float16)h0[(b0 + 1) * H_ + j];

  const h4* xrowA = (const h4*)(xproj + (size_t)b0 * G_ * NGATE) + j;
  const h4* xrowB = (const h4*)(xproj + (size_t)(b0 + 1) * G_ * NGATE) + j;
  h4 pA[4], pB[4];
#pragma unroll
  for (int d = 0; d < 4; ++d) {
    pA[d] = xrowA[(size_t)d * 64];
    pB[d] = xrowB[(size_t)d * 64];
  }

  _Float16* hrowA = hs + (size_t)b0 * (G_ * H_) + j;
  _Float16* hrowB = hrowA + (size_t)G_ * H_;

  for (int g0 = 0; g0 < G_; g0 += 4) {
#pragma unroll
    for (int d = 0; d < 4; ++d) {
      const int g = g0 + d;
      float aA[4], a2A[4], aB[4], a2B[4];
#pragma unroll
      for (int q = 0; q < 4; ++q) {
        aA[q] = (float)pA[d][q]; a2A[q] = 0.0f;
        aB[q] = (float)pB[d][q]; a2B[q] = 0.0f;
      }
      const f32x4* hpA = (const f32x4*)hsh[0];
      const f32x4* hpB = (const f32x4*)hsh[1];
#pragma unroll
      for (int k4 = 0; k4 < 4; ++k4) {
        f32x4 hvA = hpA[k4], hvB = hpB[k4];
#pragma unroll
        for (int t = 0; t < 4; ++t) {
          h2 ha = __builtin_bit_cast(h2, hvA[t]);
          h2 hb = __builtin_bit_cast(h2, hvB[t]);
#pragma unroll
          for (int q = 0; q < 4; ++q) {
            aA[q] = FDOT2(ha, w[q][k4 * 4 + t], aA[q]);
            aB[q] = FDOT2(hb, w[q][k4 * 4 + t], aB[q]);
          }
        }
      }
#pragma unroll
      for (int k4 = 4; k4 < 8; ++k4) {
        f32x4 hvA = hpA[k4], hvB = hpB[k4];
#pragma unroll
        for (int t = 0; t < 4; ++t) {
          h2 ha = __builtin_bit_cast(h2, hvA[t]);
          h2 hb = __builtin_bit_cast(h2, hvB[t]);
#pragma unroll
          for (int q = 0; q < 4; ++q) {
            a2A[q] = FDOT2(ha, w[q][k4 * 4 + t], a2A[q]);
            a2B[q] = FDOT2(hb, w[q][k4 * 4 + t], a2B[q]);
          }
        }
      }
#pragma unroll
      for (int q = 0; q < 4; ++q) { aA[q] += a2A[q]; aB[q] += a2B[q]; }

      float igA = sigf(aA[0]), igB = sigf(aB[0]);
      float fgA = sigf(aA[1]), fgB = sigf(aB[1]);
      float ggA = tanh_fast(aA[2]), ggB = tanh_fast(aB[2]);
      float ogA = sigf(aA[3]), ogB = sigf(aB[3]);
      cA = fgA * cA + igA * ggA;
      cB = fgB * cB + igB * ggB;
      float hhA = ogA * tanh_fast(cA);
      float hhB = ogB * tanh_fast(cB);
      _Float16 hfA = (_Float16)hhA;
      _Float16 hfB = (_Float16)hhB;
      hsh[0][j] = hfA;  // in-order LDS per wave orders write vs next step's reads
      hsh[1][j] = hfB;
      hrowA[(size_t)g * H_] = hfA;
      hrowB[(size_t)g * H_] = hfB;
      if (g + 4 < G_) {
        pA[d] = xrowA[(size_t)(g + 4) * 64];
        pB[d] = xrowB[(size_t)(g + 4) * 64];
      }
    }
  }
}

// ---------------- LDS-staged GEMM: part[ks][m][n] = X[m,kchunk] . W[n,kchunk]
// Low-ksplit variant: resident-stream count = rows x ksplit (was 164K at
// ksplit=32 -> HBM page thrash at ~3 TB/s). ksplit=4 => ~20K streams, each
// block walks 64 sequential 512-B stages per row. 16-KB swizzled f16 tile.
template <int N, int K, int KC>
__global__ __launch_bounds__(256) void k_gemm_lds(
    const _Float16* __restrict__ X, const float* __restrict__ W,
    float* __restrict__ part) {
  constexpr int KW = 128;  // k-floats per stage
  constexpr int KSPLIT = K / KC;
  static_assert(KC % KW == 0, "stage divisibility");
  __shared__ alignas(16) _Float16 wl[64 * KW];  // 16 KB
  const int bid = blockIdx.x;
  const int n0 = (bid / KSPLIT) * 64;
  const int ks = bid % KSPLIT;
  const int kbeg = ks * KC;
  const int lane = threadIdx.x & 63;
  const int wave = threadIdx.x >> 6;
  const int r = lane & 15;
  const int gq = lane >> 4;
  const int scol = (lane & 15) * 8;  // float col within stage (8 floats/lane)
  const int rsub = lane >> 4;        // 0..3: row-within-quad for staging

  const _Float16* xrow = X + (size_t)r * K + kbeg + 8 * gq;
  f32x4 acc[4] = {};

  for (int st = 0; st < KC / KW; ++st) {
    const int kst = kbeg + st * KW;
    // ---- stage 64x128 f32 -> f16 LDS (per wave: 16 rows, 512 B contiguous each)
#pragma unroll
    for (int it = 0; it < 4; ++it) {
      const int rr = wave * 16 + it * 4 + rsub;
      const float* src = W + (size_t)(n0 + rr) * K + kst + scol;
      f32x4 v0 = *(const f32x4*)src;
      f32x4 v1 = *(const f32x4*)(src + 4);
      half8 h;
      h[0] = (_Float16)v0[0]; h[1] = (_Float16)v0[1];
      h[2] = (_Float16)v0[2]; h[3] = (_Float16)v0[3];
      h[4] = (_Float16)v1[0]; h[5] = (_Float16)v1[1];
      h[6] = (_Float16)v1[2]; h[7] = (_Float16)v1[3];
      int byte = rr * (KW * 2) + (lane & 15) * 16;
      byte ^= (rr & 7) << 4;
      *(half8*)((char*)wl + byte) = h;
    }
    __syncthreads();
    // ---- MFMA phase: 4 k-iters of 32
#pragma unroll
    for (int k32 = 0; k32 < KW; k32 += 32) {
      int rbyte = (wave * 16 + r) * (KW * 2) + (k32 + 8 * gq) * 2;
      rbyte ^= (r & 7) << 4;
      half8 bf = *(const half8*)((const char*)wl + rbyte);
      const _Float16* xp = xrow + st * KW + k32;
#pragma unroll
      for (int mi = 0; mi < 4; ++mi) {
        half8 af = *(const half8*)(xp + (size_t)(mi * 16) * K);
        acc[mi] = __builtin_amdgcn_mfma_f32_16x16x32_f16(af, bf, acc[mi], 0, 0, 0);
      }
    }
    __syncthreads();
  }
#pragma unroll
  for (int mi = 0; mi < 4; ++mi) {
#pragma unroll
    for (int q = 0; q < 4; ++q) {
      int row = mi * 16 + gq * 4 + q;
      part[((size_t)ks * 64 + row) * N + n0 + wave * 16 + r] = acc[mi][q];
    }
  }
}

// ---------------- reduce k-split partials + bias -> f16 activations (x4 vectorized)
template <int N, int KS>
__global__ __launch_bounds__(256) void k_reduce(
    const float* __restrict__ part, const float* __restrict__ bias,
    _Float16* __restrict__ out) {
  const int idx4 = (blockIdx.x * 256 + threadIdx.x) * 4;
  const int n = idx4 % N;
  f32x4 s = *(const f32x4*)(bias + n);
#pragma unroll
  for (int ks = 0; ks < KS; ++ks) s += *(const f32x4*)(part + (size_t)ks * 64 * N + idx4);
#pragma unroll
  for (int t = 0; t < 4; ++t) out[idx4 + t] = (_Float16)s[t];
}

// ---------------- final reduce + bias + sigmoid -> fp32 output
template <int N, int KS>
__global__ __launch_bounds__(256) void k_reduce_sig(
    const float* __restrict__ part, const float* __restrict__ bias,
    float* __restrict__ out) {
  const int idx4 = (blockIdx.x * 256 + threadIdx.x) * 4;
  const int n = idx4 % N;
  f32x4 s = *(const f32x4*)(bias + n);
#pragma unroll
  for (int ks = 0; ks < KS; ++ks) s += *(const f32x4*)(part + (size_t)ks * 64 * N + idx4);
#pragma unroll
  for (int t = 0; t < 4; ++t) out[idx4 + t] = sigf(s[t]);
}

extern "C" void kernel_launch(void* const* d_in, const int* in_sizes, int n_in,
                              void* d_out, int out_size, void* d_ws, size_t ws_size,
                              hipStream_t stream) {
  const float* input = (const float*)d_in[0];
  const float* h0    = (const float*)d_in[1];
  const float* c0    = (const float*)d_in[2];
  const float* W_ih  = (const float*)d_in[3];
  const float* W_hh  = (const float*)d_in[4];
  const float* b_ih  = (const float*)d_in[5];
  const float* b_hh  = (const float*)d_in[6];
  const float* W1    = (const float*)d_in[7];
  const float* b1    = (const float*)d_in[8];
  const float* W2    = (const float*)d_in[9];
  const float* b2    = (const float*)d_in[10];
  const float* W3    = (const float*)d_in[11];
  const float* b3    = (const float*)d_in[12];
  float* out = (float*)d_out;

  uint8_t* ws = (uint8_t*)d_ws;
  float*    part  = (float*)ws;
  _Float16* xproj = (_Float16*)ws;   // [b][g][256], 16.8 MB, dead before GEMM1
  _Float16* hs    = (_Float16*)(ws + 41943040);
  _Float16* x2    = (_Float16*)(ws + 46137344);
  _Float16* x3    = (_Float16*)(ws + 46792704);

  k_xproj<<<G_, 256, 0, stream>>>(input, W_ih, b_ih, b_hh, xproj);
  k_scan<<<B_ / 2, 64, 0, stream>>>(xproj, h0, c0, W_hh, hs);
  // GEMM1: [64,32768] x W1[5120,32768]^T, ksplit=4 (KC=8192), 80 n-tiles -> 320 blocks
  k_gemm_lds<5120, 32768, 8192><<<80 * 4, 256, 0, stream>>>(hs, W1, part);
  k_reduce<5120, 4><<<(64 * 5120) / 4 / 256, 256, 0, stream>>>(part, b1, x2);
  // GEMM2: [64,5120] x W2[2560,5120]^T, ksplit=4 (KC=1280), 40 n-tiles -> 160 blocks
  k_gemm_lds<2560, 5120, 1280><<<40 * 4, 256, 0, stream>>>(x2, W2, part);
  k_reduce<2560, 4><<<(64 * 2560) / 4 / 256, 256, 0, stream>>>(part, b2, x3);
  // GEMM3: [64,2560] x W3[512,2560]^T, ksplit=5 (KC=512), 8 n-tiles -> 40 blocks
  k_gemm_lds<512, 2560, 512><<<8 * 5, 256, 0, stream>>>(x3, W3, part);
  k_reduce_sig<512, 5><<<(64 * 512) / 4 / 256, 256, 0, stream>>>(part, b3, out);
}

// Round 8
// 744.598 us; speedup vs baseline: 1.1978x; 1.1978x over previous
//
#include <hip/hip_runtime.h>
#include <hip/hip_fp16.h>

#define G_ 512
#define B_ 64
#define I_ 32
#define H_ 64
#define NGATE 256  // 4*H

typedef _Float16 half8 __attribute__((ext_vector_type(8)));
typedef _Float16 h4 __attribute__((ext_vector_type(4)));
typedef float f32x4 __attribute__((ext_vector_type(4)));

__device__ __forceinline__ float sigf(float x) {
  return 1.0f / (1.0f + __expf(-x));
}
__device__ __forceinline__ float tanh_fast(float x) {
  x = fminf(fmaxf(x, -15.0f), 15.0f);
  float e = __expf(2.0f * x);
  return (e - 1.0f) / (e + 1.0f);
}

// ---------------- K1: xproj[b][g][col*4+q]  (h4-per-(b,g,col): all 4 gates contiguous)
__global__ __launch_bounds__(256) void k_xproj(
    const float* __restrict__ input, const float* __restrict__ W_ih,
    const float* __restrict__ b_ih, const float* __restrict__ b_hh,
    _Float16* __restrict__ xproj) {
  const int g = blockIdx.x;
  const int t = threadIdx.x;
  const int col = t >> 2;
  const int q = t & 3;
  const int row = q * H_ + col;  // gate-row in torch i,f,g,o order
  __shared__ alignas(16) float inp[B_ * I_];
  const float* ing = input + (size_t)g * (B_ * I_);
#pragma unroll
  for (int u = 0; u < (B_ * I_) / 256; ++u) inp[u * 256 + t] = ing[u * 256 + t];
  float w[I_];
#pragma unroll
  for (int k = 0; k < I_; k += 4) {
    f32x4 v = *(const f32x4*)(W_ih + (size_t)row * I_ + k);
    w[k] = v[0]; w[k + 1] = v[1]; w[k + 2] = v[2]; w[k + 3] = v[3];
  }
  const float bias = b_ih[row] + b_hh[row];
  __syncthreads();
  for (int b = 0; b < B_; ++b) {
    float a0 = bias, a1 = 0.f, a2 = 0.f, a3 = 0.f;
#pragma unroll
    for (int k = 0; k < I_; k += 4) {
      f32x4 iv = *(const f32x4*)&inp[b * I_ + k];
      a0 += iv[0] * w[k]; a1 += iv[1] * w[k + 1];
      a2 += iv[2] * w[k + 2]; a3 += iv[3] * w[k + 3];
    }
    xproj[((size_t)b * G_ + g) * NGATE + t] = (_Float16)((a0 + a1) + (a2 + a3));
  }
}

// ---------------- K2: MFMA LSTM scan. 4 blocks x 16 batch rows x 8 waves.
// Wave (w = wid&3) owns gate-cols w*16..w*16+15 of ALL 4 gates; B-frags of
// W_hh live in VGPRs; A = h tile in double-buffered XOR-swizzled LDS; acc is
// initialized from a depth-4 xproj register ring (no vmcnt drain: raw
// s_barrier + lgkmcnt(0) only). Wave halves (half = wid>>2) split the
// activation rows. Fragment mappings copied from the proven k_gemm:
//   C[row = gq*4+q'][col = w*16 + r],  af = h[r][k],  bf = W_hh[gaterow][k].
__global__ __launch_bounds__(512) void k_scan(
    const _Float16* __restrict__ xproj, const float* __restrict__ h0,
    const float* __restrict__ c0, const float* __restrict__ W_hh,
    _Float16* __restrict__ hs) {
  const int bb = blockIdx.x;      // batch rows bb*16 .. bb*16+15
  const int tid = threadIdx.x;
  const int wid = tid >> 6;       // 0..7
  const int lane = tid & 63;
  const int w = wid & 3;          // col-group
  const int half = wid >> 2;      // activation half: q' in {2h, 2h+1}
  const int r = lane & 15;
  const int gq = lane >> 4;
  const int jj = w * 16 + r;      // gate column owned at C col

  __shared__ alignas(16) _Float16 hl[2][16 * 64];  // 4 KB double buffer

  // B-frags: bf[gate][kk] = W_hh[gate*64 + jj][kk*32 + 8*gq .. +7] (f32->f16)
  half8 bf[4][2];
#pragma unroll
  for (int gate = 0; gate < 4; ++gate)
#pragma unroll
    for (int kk = 0; kk < 2; ++kk) {
      const float* src = W_hh + (size_t)(gate * H_ + jj) * H_ + kk * 32 + 8 * gq;
      f32x4 v0 = *(const f32x4*)src;
      f32x4 v1 = *(const f32x4*)(src + 4);
      half8 h;
      h[0] = (_Float16)v0[0]; h[1] = (_Float16)v0[1];
      h[2] = (_Float16)v0[2]; h[3] = (_Float16)v0[3];
      h[4] = (_Float16)v1[0]; h[5] = (_Float16)v1[1];
      h[6] = (_Float16)v1[2]; h[7] = (_Float16)v1[3];
      bf[gate][kk] = h;
    }

  // h0 -> hl[0] (swizzled); 512 threads x 2 values = 16x64
#pragma unroll
  for (int u = 0; u < 2; ++u) {
    int v = tid * 2 + u;
    int row = v >> 6, j = v & 63;
    _Float16 hv = (_Float16)h0[(size_t)(bb * 16 + row) * H_ + j];
    int byte = ((row * 64 + j) * 2) ^ ((row & 7) << 4);
    *(_Float16*)((char*)hl[0] + byte) = hv;
  }

  // c state for this wave's two activation rows: q' = 2*half + e
  float cst[2];
#pragma unroll
  for (int e = 0; e < 2; ++e)
    cst[e] = c0[(size_t)(bb * 16 + gq * 4 + 2 * half + e) * H_ + jj];

  // xproj ring pointers: xr[q'] -> h4 stream (stride 64 h4 per g)
  const h4* xr[4];
#pragma unroll
  for (int q = 0; q < 4; ++q)
    xr[q] = (const h4*)(xproj + (size_t)(bb * 16 + gq * 4 + q) * G_ * NGATE) + jj;
  h4 pA[4], pB[4], pC[4], pD[4];
#pragma unroll
  for (int q = 0; q < 4; ++q) {
    pA[q] = xr[q][0 * 64];
    pB[q] = xr[q][1 * 64];
    pC[q] = xr[q][2 * 64];
    pD[q] = xr[q][3 * 64];
  }

  __syncthreads();

#define ACT(qp, e, gg, NXT)                                                  \
  {                                                                          \
    float iv = sigf(acc[0][qp]);                                             \
    float fv = sigf(acc[1][qp]);                                             \
    float gv = tanh_fast(acc[2][qp]);                                        \
    float ov = sigf(acc[3][qp]);                                             \
    cst[e] = fv * cst[e] + iv * gv;                                          \
    float hh = ov * tanh_fast(cst[e]);                                       \
    _Float16 hf = (_Float16)hh;                                              \
    int row_ = gq * 4 + (qp);                                                \
    int byte_ = ((row_ * 64 + jj) * 2) ^ ((row_ & 7) << 4);                  \
    *(_Float16*)((char*)hl[NXT] + byte_) = hf;                               \
    hs[(size_t)(bb * 16 + row_) * (G_ * H_) + (size_t)(gg)*H_ + jj] = hf;    \
  }

#define STEP(gg, CUR, NXT, P)                                                \
  {                                                                          \
    int b0_ = ((r * 64 + 0 * 32 + 8 * gq) * 2) ^ ((r & 7) << 4);             \
    int b1_ = ((r * 64 + 1 * 32 + 8 * gq) * 2) ^ ((r & 7) << 4);             \
    half8 af0 = *(const half8*)((const char*)hl[CUR] + b0_);                 \
    half8 af1 = *(const half8*)((const char*)hl[CUR] + b1_);                 \
    f32x4 acc[4];                                                            \
    _Pragma("unroll")                                                        \
    for (int gate = 0; gate < 4; ++gate) {                                   \
      acc[gate] = f32x4{(float)P[0][gate], (float)P[1][gate],                \
                        (float)P[2][gate], (float)P[3][gate]};               \
      acc[gate] = __builtin_amdgcn_mfma_f32_16x16x32_f16(af0, bf[gate][0],   \
                                                         acc[gate], 0, 0, 0);\
      acc[gate] = __builtin_amdgcn_mfma_f32_16x16x32_f16(af1, bf[gate][1],   \
                                                         acc[gate], 0, 0, 0);\
    }                                                                        \
    if ((gg) + 4 < G_) {                                                     \
      _Pragma("unroll")                                                      \
      for (int q = 0; q < 4; ++q) P[q] = xr[q][((gg) + 4) * 64];             \
    }                                                                        \
    if (half == 0) {                                                         \
      ACT(0, 0, gg, NXT);                                                    \
      ACT(1, 1, gg, NXT);                                                    \
    } else {                                                                 \
      ACT(2, 0, gg, NXT);                                                    \
      ACT(3, 1, gg, NXT);                                                    \
    }                                                                        \
    asm volatile("s_waitcnt lgkmcnt(0)" ::: "memory");                       \
    __builtin_amdgcn_s_barrier();                                            \
    __builtin_amdgcn_sched_barrier(0);                                       \
  }

  for (int g = 0; g < G_; g += 4) {
    STEP(g + 0, 0, 1, pA);
    STEP(g + 1, 1, 0, pB);
    STEP(g + 2, 0, 1, pC);
    STEP(g + 3, 1, 0, pD);
  }
#undef STEP
#undef ACT
}

// ---------------- LDS-staged GEMM (round-6 proven version, ksplit via NTILES)
template <int N, int K, int KC, int NTILES>
__global__ __launch_bounds__(256) void k_gemm_lds(
    const _Float16* __restrict__ X, const float* __restrict__ W,
    float* __restrict__ part) {
  constexpr int KW = 128;  // k-floats per stage
  static_assert(KC % KW == 0, "stage divisibility");
  __shared__ alignas(16) _Float16 wl[64 * KW];  // 16 KB
  const int bid = blockIdx.x;
  const int n0 = (bid % NTILES) * 64;
  const int ks = bid / NTILES;
  const int kbeg = ks * KC;
  const int lane = threadIdx.x & 63;
  const int wave = threadIdx.x >> 6;
  const int r = lane & 15;
  const int gq = lane >> 4;
  const int scol = (lane & 15) * 8;
  const int rsub = lane >> 4;

  const _Float16* xrow = X + (size_t)r * K + kbeg + 8 * gq;
  f32x4 acc[4] = {};

  for (int st = 0; st < KC / KW; ++st) {
    const int kst = kbeg + st * KW;
#pragma unroll
    for (int it = 0; it < 4; ++it) {
      const int rr = wave * 16 + it * 4 + rsub;
      const float* src = W + (size_t)(n0 + rr) * K + kst + scol;
      f32x4 v0 = *(const f32x4*)src;
      f32x4 v1 = *(const f32x4*)(src + 4);
      half8 h;
      h[0] = (_Float16)v0[0]; h[1] = (_Float16)v0[1];
      h[2] = (_Float16)v0[2]; h[3] = (_Float16)v0[3];
      h[4] = (_Float16)v1[0]; h[5] = (_Float16)v1[1];
      h[6] = (_Float16)v1[2]; h[7] = (_Float16)v1[3];
      int byte = rr * (KW * 2) + (lane & 15) * 16;
      byte ^= (rr & 7) << 4;
      *(half8*)((char*)wl + byte) = h;
    }
    __syncthreads();
#pragma unroll
    for (int k32 = 0; k32 < KW; k32 += 32) {
      int rbyte = (wave * 16 + r) * (KW * 2) + (k32 + 8 * gq) * 2;
      rbyte ^= (r & 7) << 4;
      half8 bfv = *(const half8*)((const char*)wl + rbyte);
      const _Float16* xp = xrow + st * KW + k32;
#pragma unroll
      for (int mi = 0; mi < 4; ++mi) {
        half8 af = *(const half8*)(xp + (size_t)(mi * 16) * K);
        acc[mi] = __builtin_amdgcn_mfma_f32_16x16x32_f16(af, bfv, acc[mi], 0, 0, 0);
      }
    }
    __syncthreads();
  }
#pragma unroll
  for (int mi = 0; mi < 4; ++mi) {
#pragma unroll
    for (int q = 0; q < 4; ++q) {
      int row = mi * 16 + gq * 4 + q;
      part[((size_t)ks * 64 + row) * N + n0 + wave * 16 + r] = acc[mi][q];
    }
  }
}

// ---------------- reduce k-split partials + bias -> f16 activations (x4 vectorized)
template <int N, int KS>
__global__ __launch_bounds__(256) void k_reduce(
    const float* __restrict__ part, const float* __restrict__ bias,
    _Float16* __restrict__ out) {
  const int idx4 = (blockIdx.x * 256 + threadIdx.x) * 4;
  const int n = idx4 % N;
  f32x4 s = *(const f32x4*)(bias + n);
#pragma unroll
  for (int ks = 0; ks < KS; ++ks) s += *(const f32x4*)(part + (size_t)ks * 64 * N + idx4);
#pragma unroll
  for (int t = 0; t < 4; ++t) out[idx4 + t] = (_Float16)s[t];
}

// ---------------- final reduce + bias + sigmoid -> fp32 output
template <int N, int KS>
__global__ __launch_bounds__(256) void k_reduce_sig(
    const float* __restrict__ part, const float* __restrict__ bias,
    float* __restrict__ out) {
  const int idx4 = (blockIdx.x * 256 + threadIdx.x) * 4;
  const int n = idx4 % N;
  f32x4 s = *(const f32x4*)(bias + n);
#pragma unroll
  for (int ks = 0; ks < KS; ++ks) s += *(const f32x4*)(part + (size_t)ks * 64 * N + idx4);
#pragma unroll
  for (int t = 0; t < 4; ++t) out[idx4 + t] = sigf(s[t]);
}

extern "C" void kernel_launch(void* const* d_in, const int* in_sizes, int n_in,
                              void* d_out, int out_size, void* d_ws, size_t ws_size,
                              hipStream_t stream) {
  const float* input = (const float*)d_in[0];
  const float* h0    = (const float*)d_in[1];
  const float* c0    = (const float*)d_in[2];
  const float* W_ih  = (const float*)d_in[3];
  const float* W_hh  = (const float*)d_in[4];
  const float* b_ih  = (const float*)d_in[5];
  const float* b_hh  = (const float*)d_in[6];
  const float* W1    = (const float*)d_in[7];
  const float* b1    = (const float*)d_in[8];
  const float* W2    = (const float*)d_in[9];
  const float* b2    = (const float*)d_in[10];
  const float* W3    = (const float*)d_in[11];
  const float* b3    = (const float*)d_in[12];
  float* out = (float*)d_out;

  uint8_t* ws = (uint8_t*)d_ws;
  float*    part  = (float*)ws;
  _Float16* xproj = (_Float16*)ws;   // [b][g][256], 16.8 MB, dead before GEMM1
  _Float16* hs    = (_Float16*)(ws + 41943040);
  _Float16* x2    = (_Float16*)(ws + 46137344);
  _Float16* x3    = (_Float16*)(ws + 46792704);

  k_xproj<<<G_, 256, 0, stream>>>(input, W_ih, b_ih, b_hh, xproj);
  k_scan<<<4, 512, 0, stream>>>(xproj, h0, c0, W_hh, hs);
  // GEMM1: [64,32768] x W1[5120,32768]^T, ksplit=32 (KC=1024), 80 n-tiles
  k_gemm_lds<5120, 32768, 1024, 80><<<80 * 32, 256, 0, stream>>>(hs, W1, part);
  k_reduce<5120, 32><<<(64 * 5120) / 4 / 256, 256, 0, stream>>>(part, b1, x2);
  // GEMM2: [64,5120] x W2[2560,5120]^T, ksplit=8 (KC=640), 40 n-tiles
  k_gemm_lds<2560, 5120, 640, 40><<<40 * 8, 256, 0, stream>>>(x2, W2, part);
  k_reduce<2560, 8><<<(64 * 2560) / 4 / 256, 256, 0, stream>>>(part, b2, x3);
  // GEMM3: [64,2560] x W3[512,2560]^T, ksplit=10 (KC=256), 8 n-tiles
  k_gemm_lds<512, 2560, 256, 8><<<8 * 10, 256, 0, stream>>>(x3, W3, part);
  k_reduce_sig<512, 10><<<(64 * 512) / 4 / 256, 256, 0, stream>>>(part, b3, out);
}

// Round 9
// 489.576 us; speedup vs baseline: 1.8217x; 1.5209x over previous
//
#include <hip/hip_runtime.h>
#include <hip/hip_fp16.h>

#define G_ 512
#define B_ 64
#define I_ 32
#define H_ 64
#define NGATE 256  // 4*H

typedef _Float16 half8 __attribute__((ext_vector_type(8)));
typedef _Float16 h4 __attribute__((ext_vector_type(4)));
typedef _Float16 h2 __attribute__((ext_vector_type(2)));
typedef float f32x4 __attribute__((ext_vector_type(4)));

#if __has_builtin(__builtin_amdgcn_fdot2)
#define FDOT2(a, b, c) __builtin_amdgcn_fdot2((a), (b), (c), false)
#else
#define FDOT2(a, b, c) ((c) + (float)(a)[0] * (float)(b)[0] + (float)(a)[1] * (float)(b)[1])
#endif

__device__ __forceinline__ float sigf(float x) {
  return 1.0f / (1.0f + __expf(-x));
}
__device__ __forceinline__ float tanh_fast(float x) {
  x = fminf(fmaxf(x, -15.0f), 15.0f);
  float e = __expf(2.0f * x);
  return (e - 1.0f) / (e + 1.0f);
}

// ---------------- K1: xproj[b][g][col*4+q]  (coalesced; scan reads one h4/lane)
__global__ __launch_bounds__(256) void k_xproj(
    const float* __restrict__ input, const float* __restrict__ W_ih,
    const float* __restrict__ b_ih, const float* __restrict__ b_hh,
    _Float16* __restrict__ xproj) {
  const int g = blockIdx.x;
  const int t = threadIdx.x;
  const int col = t >> 2;
  const int q = t & 3;
  const int row = q * H_ + col;  // gate-row in torch i,f,g,o order
  __shared__ alignas(16) float inp[B_ * I_];
  const float* ing = input + (size_t)g * (B_ * I_);
#pragma unroll
  for (int u = 0; u < (B_ * I_) / 256; ++u) inp[u * 256 + t] = ing[u * 256 + t];
  float w[I_];
#pragma unroll
  for (int k = 0; k < I_; k += 4) {
    f32x4 v = *(const f32x4*)(W_ih + (size_t)row * I_ + k);
    w[k] = v[0]; w[k + 1] = v[1]; w[k + 2] = v[2]; w[k + 3] = v[3];
  }
  const float bias = b_ih[row] + b_hh[row];
  __syncthreads();
  for (int b = 0; b < B_; ++b) {
    float a0 = bias, a1 = 0.f, a2 = 0.f, a3 = 0.f;
#pragma unroll
    for (int k = 0; k < I_; k += 4) {
      f32x4 iv = *(const f32x4*)&inp[b * I_ + k];
      a0 += iv[0] * w[k]; a1 += iv[1] * w[k + 1];
      a2 += iv[2] * w[k + 2]; a3 += iv[3] * w[k + 3];
    }
    xproj[((size_t)b * G_ + g) * NGATE + t] = (_Float16)((a0 + a1) + (a2 + a3));
  }
}

// ---------------- R5-proven scan body (barrier-free, depth-8 xproj ring)
__device__ __forceinline__ void scan_row(
    int b, int j, const _Float16* __restrict__ xproj,
    const float* __restrict__ h0, const float* __restrict__ c0,
    const float* __restrict__ W_hh, _Float16* __restrict__ hs,
    _Float16* hsh) {
  h2 w[4][32];
#pragma unroll
  for (int q = 0; q < 4; ++q) {
    const f32x4* wr = (const f32x4*)(W_hh + (size_t)(q * H_ + j) * H_);
#pragma unroll
    for (int kk = 0; kk < 16; ++kk) {
      f32x4 v = wr[kk];
      h2 t0, t1;
      t0[0] = (_Float16)v[0]; t0[1] = (_Float16)v[1];
      t1[0] = (_Float16)v[2]; t1[1] = (_Float16)v[3];
      w[2 * kk & 0 ? 0 : 0][0] = w[0][0];  // no-op to appease nothing
      w[q][2 * kk] = t0;
      w[q][2 * kk + 1] = t1;
    }
  }
  float c = c0[b * H_ + j];
  hsh[j] = (_Float16)h0[b * H_ + j];

  const h4* xrow = (const h4*)(xproj + (size_t)b * G_ * NGATE) + j;
  h4 p[8];
#pragma unroll
  for (int d = 0; d < 8; ++d) p[d] = xrow[(size_t)d * 64];

  _Float16* hrow = hs + (size_t)b * (G_ * H_) + j;

  for (int g0 = 0; g0 < G_; g0 += 8) {
#pragma unroll
    for (int d = 0; d < 8; ++d) {
      const int g = g0 + d;
      float a[4], a2[4];
#pragma unroll
      for (int q = 0; q < 4; ++q) { a[q] = (float)p[d][q]; a2[q] = 0.0f; }
      const f32x4* hp4 = (const f32x4*)hsh;
#pragma unroll
      for (int k4 = 0; k4 < 4; ++k4) {
        f32x4 hv4 = hp4[k4];
#pragma unroll
        for (int t = 0; t < 4; ++t) {
          h2 hv = __builtin_bit_cast(h2, hv4[t]);
#pragma unroll
          for (int q = 0; q < 4; ++q) a[q] = FDOT2(hv, w[q][k4 * 4 + t], a[q]);
        }
      }
#pragma unroll
      for (int k4 = 4; k4 < 8; ++k4) {
        f32x4 hv4 = hp4[k4];
#pragma unroll
        for (int t = 0; t < 4; ++t) {
          h2 hv = __builtin_bit_cast(h2, hv4[t]);
#pragma unroll
          for (int q = 0; q < 4; ++q) a2[q] = FDOT2(hv, w[q][k4 * 4 + t], a2[q]);
        }
      }
#pragma unroll
      for (int q = 0; q < 4; ++q) a[q] += a2[q];

      float ig = sigf(a[0]);
      float fg = sigf(a[1]);
      float gg = tanh_fast(a[2]);
      float og = sigf(a[3]);
      c = fg * c + ig * gg;
      float hh = og * tanh_fast(c);
      _Float16 hf = (_Float16)hh;
      hsh[j] = hf;
      hrow[(size_t)g * H_] = hf;
      if (g + 8 < G_) p[d] = xrow[(size_t)(g + 8) * 64];
    }
  }
}

// ---------------- f32 -> f16 streaming convert (vec8 per thread-iter)
__device__ __forceinline__ void conv_loop(
    const float* __restrict__ src, _Float16* __restrict__ dst, int nvec,
    int gtid, int gstride) {
  for (int i = gtid; i < nvec; i += gstride) {
    const f32x4* s = (const f32x4*)(src + (size_t)i * 8);
    f32x4 v0 = s[0];
    f32x4 v1 = s[1];
    half8 h;
    h[0] = (_Float16)v0[0]; h[1] = (_Float16)v0[1];
    h[2] = (_Float16)v0[2]; h[3] = (_Float16)v0[3];
    h[4] = (_Float16)v1[0]; h[5] = (_Float16)v1[1];
    h[6] = (_Float16)v1[2]; h[7] = (_Float16)v1[3];
    *(half8*)(dst + (size_t)i * 8) = h;
  }
}

#define NCONV 2048

// ---------------- K2: fused scan (blocks 0-63, wave 0) + weight convert (blocks 64+)
// Independent work items in one kernel: the 1.09-GB f32->f16 weight conversion
// streams on the ~192 CUs (and spare waves) the latency-bound scan leaves idle.
// No inter-block dependencies; deterministic.
__global__ __launch_bounds__(256) void k_scan_conv(
    const _Float16* __restrict__ xproj, const float* __restrict__ h0,
    const float* __restrict__ c0, const float* __restrict__ W_hh,
    _Float16* __restrict__ hs,
    const float* __restrict__ W1, _Float16* __restrict__ W1h,
    const float* __restrict__ W2, _Float16* __restrict__ W2h,
    const float* __restrict__ W3, _Float16* __restrict__ W3h) {
  __shared__ alignas(16) _Float16 hsh[H_];
  const int bid = blockIdx.x;
  if (bid < B_) {
    if (threadIdx.x < 64)
      scan_row(bid, threadIdx.x, xproj, h0, c0, W_hh, hs, hsh);
    return;
  }
  const int gtid = (bid - B_) * 256 + threadIdx.x;
  const int gstride = NCONV * 256;
  conv_loop(W1, W1h, (5120 * 32768) / 8, gtid, gstride);
  conv_loop(W2, W2h, (2560 * 5120) / 8, gtid, gstride);
  conv_loop(W3, W3h, (512 * 2560) / 8, gtid, gstride);
}

// ---------------- LDS-staged GEMM on f16 weights.
// part[ks][m][n] = X[m,kchunk] . Wh[n,kchunk]; KW = f16 elems per stage row.
template <int N, int K, int KC, int NTILES, int KW>
__global__ __launch_bounds__(256) void k_gemm_h(
    const _Float16* __restrict__ X, const _Float16* __restrict__ Wh,
    float* __restrict__ part) {
  constexpr int ROWB = KW * 2;       // bytes per LDS row
  constexpr int SLOTS = ROWB / 16;   // 16-B slots per row
  constexpr int RPP = 64 / SLOTS;    // rows staged per wave-pass
  constexpr int NPASS = 16 / RPP;    // passes per wave (16 rows/wave)
  static_assert(KC % KW == 0, "stage divisibility");
  __shared__ alignas(16) _Float16 wl[64 * KW];
  const int bid = blockIdx.x;
  const int n0 = (bid % NTILES) * 64;
  const int ks = bid / NTILES;
  const int kbeg = ks * KC;
  const int lane = threadIdx.x & 63;
  const int wave = threadIdx.x >> 6;
  const int r = lane & 15;
  const int gq = lane >> 4;
  const int s = lane % SLOTS;        // 16-B slot within row
  const int ro = lane / SLOTS;       // row-within-pass

  const _Float16* xrow = X + (size_t)r * K + kbeg + 8 * gq;
  f32x4 acc[4] = {};

  for (int st = 0; st < KC / KW; ++st) {
    const int kst = kbeg + st * KW;
    // ---- stage 64 x KW f16 (per pass: RPP rows, ROWB contiguous bytes each)
#pragma unroll
    for (int pass = 0; pass < NPASS; ++pass) {
      const int rr = wave * 16 + pass * RPP + ro;
      half8 hv = *(const half8*)(Wh + (size_t)(n0 + rr) * K + kst + s * 8);
      int byte = rr * ROWB + s * 16;
      byte ^= (rr & 7) << 4;
      *(half8*)((char*)wl + byte) = hv;
    }
    __syncthreads();
    // ---- MFMA phase
#pragma unroll
    for (int k32 = 0; k32 < KW; k32 += 32) {
      int rbyte = (wave * 16 + r) * ROWB + (k32 + 8 * gq) * 2;
      rbyte ^= (r & 7) << 4;
      half8 bfv = *(const half8*)((const char*)wl + rbyte);
      const _Float16* xp = xrow + st * KW + k32;
#pragma unroll
      for (int mi = 0; mi < 4; ++mi) {
        half8 af = *(const half8*)(xp + (size_t)(mi * 16) * K);
        acc[mi] = __builtin_amdgcn_mfma_f32_16x16x32_f16(af, bfv, acc[mi], 0, 0, 0);
      }
    }
    __syncthreads();
  }
#pragma unroll
  for (int mi = 0; mi < 4; ++mi) {
#pragma unroll
    for (int q = 0; q < 4; ++q) {
      int row = mi * 16 + gq * 4 + q;
      part[((size_t)ks * 64 + row) * N + n0 + wave * 16 + r] = acc[mi][q];
    }
  }
}

// ---------------- reduce k-split partials + bias -> f16 activations (x4 vectorized)
template <int N, int KS>
__global__ __launch_bounds__(256) void k_reduce(
    const float* __restrict__ part, const float* __restrict__ bias,
    _Float16* __restrict__ out) {
  const int idx4 = (blockIdx.x * 256 + threadIdx.x) * 4;
  const int n = idx4 % N;
  f32x4 s = *(const f32x4*)(bias + n);
#pragma unroll
  for (int ks = 0; ks < KS; ++ks) s += *(const f32x4*)(part + (size_t)ks * 64 * N + idx4);
#pragma unroll
  for (int t = 0; t < 4; ++t) out[idx4 + t] = (_Float16)s[t];
}

// ---------------- final reduce + bias + sigmoid -> fp32 output
template <int N, int KS>
__global__ __launch_bounds__(256) void k_reduce_sig(
    const float* __restrict__ part, const float* __restrict__ bias,
    float* __restrict__ out) {
  const int idx4 = (blockIdx.x * 256 + threadIdx.x) * 4;
  const int n = idx4 % N;
  f32x4 s = *(const f32x4*)(bias + n);
#pragma unroll
  for (int ks = 0; ks < KS; ++ks) s += *(const f32x4*)(part + (size_t)ks * 64 * N + idx4);
#pragma unroll
  for (int t = 0; t < 4; ++t) out[idx4 + t] = sigf(s[t]);
}

extern "C" void kernel_launch(void* const* d_in, const int* in_sizes, int n_in,
                              void* d_out, int out_size, void* d_ws, size_t ws_size,
                              hipStream_t stream) {
  const float* input = (const float*)d_in[0];
  const float* h0    = (const float*)d_in[1];
  const float* c0    = (const float*)d_in[2];
  const float* W_ih  = (const float*)d_in[3];
  const float* W_hh  = (const float*)d_in[4];
  const float* b_ih  = (const float*)d_in[5];
  const float* b_hh  = (const float*)d_in[6];
  const float* W1    = (const float*)d_in[7];
  const float* b1    = (const float*)d_in[8];
  const float* W2    = (const float*)d_in[9];
  const float* b2    = (const float*)d_in[10];
  const float* W3    = (const float*)d_in[11];
  const float* b3    = (const float*)d_in[12];
  float* out = (float*)d_out;

  // Workspace layout (~411.5 MB of ~2.6 GB):
  //   [0, 41943040)              part (<= 32 x 64 x 5120 fp32); xproj overlay (16.8 MB)
  //   [41943040, 46137344)       hs_f16  [64][32768]
  //   [46137344, 46792704)       x2_f16  [64][5120]
  //   [46792704, 47120384)       x3_f16  [64][2560]
  //   [47120384, 382664704)      W1h f16 [5120][32768]
  //   [382664704, 408879104)     W2h f16 [2560][5120]
  //   [408879104, 411500544)     W3h f16 [512][2560]
  uint8_t* ws = (uint8_t*)d_ws;
  float*    part  = (float*)ws;
  _Float16* xproj = (_Float16*)ws;
  _Float16* hs    = (_Float16*)(ws + 41943040);
  _Float16* x2    = (_Float16*)(ws + 46137344);
  _Float16* x3    = (_Float16*)(ws + 46792704);
  _Float16* W1h   = (_Float16*)(ws + 47120384);
  _Float16* W2h   = (_Float16*)(ws + 382664704);
  _Float16* W3h   = (_Float16*)(ws + 408879104);

  k_xproj<<<G_, 256, 0, stream>>>(input, W_ih, b_ih, b_hh, xproj);
  // Fused: blocks 0-63 run the proven R5 scan; blocks 64.. stream-convert W1/W2/W3
  // to f16 (hidden under the scan's 242 us — scan uses <1% of HBM BW).
  k_scan_conv<<<B_ + NCONV, 256, 0, stream>>>(xproj, h0, c0, W_hh, hs,
                                              W1, W1h, W2, W2h, W3, W3h);
  // GEMM1: [64,32768] x W1h[5120,32768]^T, ksplit=32 (KC=1024), KW=256
  k_gemm_h<5120, 32768, 1024, 80, 256><<<80 * 32, 256, 0, stream>>>(hs, W1h, part);
  k_reduce<5120, 32><<<(64 * 5120) / 4 / 256, 256, 0, stream>>>(part, b1, x2);
  // GEMM2: [64,5120] x W2h[2560,5120]^T, ksplit=8 (KC=640), KW=128
  k_gemm_h<2560, 5120, 640, 40, 128><<<40 * 8, 256, 0, stream>>>(x2, W2h, part);
  k_reduce<2560, 8><<<(64 * 2560) / 4 / 256, 256, 0, stream>>>(part, b2, x3);
  // GEMM3: [64,2560] x W3h[512,2560]^T, ksplit=10 (KC=256), KW=128
  k_gemm_h<512, 2560, 256, 8, 128><<<8 * 10, 256, 0, stream>>>(x3, W3h, part);
  k_reduce_sig<512, 10><<<(64 * 512) / 4 / 256, 256, 0, stream>>>(part, b3, out);
}